// Round 9
// baseline (203.730 us; speedup 1.0000x reference)
//
#include <hip/hip_runtime.h>
#include <math.h>

// DCN v2: B=8, C=128, O=128, H=W=64, k=3, dil=1, dg=1, stride=1, pad=1.
// R9: fixes R8's wave-level fallback catastrophe (85% of task-waves took the
// 64-global-gather path). Now: corner reads ALWAYS from LDS band with clamped
// indices; rare out-of-band rows overwritten per-LANE from global (~2% lanes).
// Plus 16B-aligned ash (stride 88 dwords -> ds_read/write_b128) and pband
// stride 660 (aligned uint4 staging writes).
constexpr int Bn = 8, Cn = 128, On = 128, Hn = 64, Wn = 64;
constexpr int KK = 9, PAD = 1, BDIM = 256;
constexpr int PXB = 32;              // pixels per block (half row)
constexpr int CG = 16;               // channels per granule
constexpr int NG = Cn / CG;          // 8
constexpr int KG = 160;              // 144 real k-slices + 16 zero pad
constexpr int KTOT = NG * KG;        // 1280
constexpr int BANDH = 10;            // band rows
constexpr int XSTP = 660;            // pband pair stride (u32), mod4=0 for b128
constexpr int ASTW = 88;             // ash k-stride in u32 (=176 bf16), 16B-aligned
constexpr int ME = KK * PXB;         // 288 (tap,px) tasks per block

typedef __attribute__((ext_vector_type(8))) short bf16x8;
typedef __attribute__((ext_vector_type(4))) float f32x4;
typedef unsigned short u16;
typedef unsigned int u32;

__device__ inline u16 f2bf(float f) {   // RNE f32->bf16
    union { float f; u32 u; } v; v.f = f;
    return (u16)((v.u + 0x7FFFu + ((v.u >> 16) & 1u)) >> 16);
}
__device__ inline u32 pk2bf(float a, float b) {   // low16 = bf16(a)
    return (u32)f2bf(a) | ((u32)f2bf(b) << 16);
}
__device__ inline float bflo(u32 w) { return __uint_as_float(w << 16); }
__device__ inline float bfhi(u32 w) { return __uint_as_float(w & 0xFFFF0000u); }

// weight [O][C*9] fp32 -> wbf [O][KTOT] bf16, k' = g*KG + t*16 + cl
__global__ void wprep_kernel(const float* __restrict__ w, u16* __restrict__ wbf) {
    const int e = blockIdx.x * BDIM + threadIdx.x;    // < 163840
    const int o  = e / KTOT;
    const int kp = e - o * KTOT;
    const int g  = kp / KG;
    const int r  = kp - g * KG;
    const int t  = r >> 4;
    const int cl = r & 15;
    float v = 0.f;
    if (t < KK) v = w[o * (Cn * KK) + (g * CG + cl) * KK + t];
    wbf[e] = f2bf(v);
}

__global__ __launch_bounds__(BDIM, 4)
void dcn_mfma_kernel(const float* __restrict__ x,
                     const float* __restrict__ offs,
                     const float* __restrict__ mask,
                     const u16*   __restrict__ wbf,
                     const float* __restrict__ bias,
                     float* __restrict__ out)
{
    __shared__ __align__(16) u32 pband[8 * XSTP];   // 21,120 B
    __shared__ __align__(16) u32 ashw[PXB * ASTW];  // 11,264 B (tot 32.4 KB)

    const int tid    = threadIdx.x;
    const int b      = blockIdx.x & 7;          // batch<->XCD affinity
    const int rem    = blockIdx.x >> 3;
    const int h      = rem >> 1;
    const int pxbase = (rem & 1) * PXB;
    const int r0     = min(max(h - 4, 0), Hn - BANDH);

    // band task map: tau = tid + it*256 -> px4=tau&15, pair const, row=tau>>7
    const int s_px4  = tid & 15;
    const int s_pair = (tid >> 4) & 7;
    float4 bnda[5], bndb[5];
    {   // issue granule-0 band loads early
        #pragma unroll
        for (int it = 0; it < 5; ++it) {
            const int row = (tid + it * BDIM) >> 7;
            const float* base = x + (((size_t)(b * Cn + 2 * s_pair)) << 12)
                                + (r0 + row) * Wn + (s_px4 << 2);
            bnda[it] = *(const float4*)base;
            bndb[it] = *(const float4*)(base + 4096);
        }
    }

    // ---- meta in registers: weights mw, oob-coded coords mq, CLAMPED LDS idx mi ----
    float4 mw[2]; int2 mq[2]; int2 mi[2];
    #pragma unroll
    for (int it = 0; it < 2; ++it) {
        mw[it] = make_float4(0.f, 0.f, 0.f, 0.f);
        mq[it] = make_int2(0, 0);
        mi[it] = make_int2(7, 7);
        const int e = tid + it * BDIM;
        if (e < ME) {
            const int t = e >> 5, px = e & 31, pg = pxbase + px;
            const int ty = t / 3, tx = t - ty * 3;
            const float oy = offs[((b * 18 + 2 * t    ) * Hn + h) * Wn + pg];
            const float ox = offs[((b * 18 + 2 * t + 1) * Hn + h) * Wn + pg];
            const float m  = mask[((b * KK + t) * Hn + h) * Wn + pg];
            const float py = (float)(h - PAD + ty) + oy;
            const float qx = (float)(pg - PAD + tx) + ox;
            const float fy = floorf(py), fx = floorf(qx);
            const float wy1 = py - fy, wx1 = qx - fx;
            const float wy0 = 1.f - wy1, wx0 = 1.f - wx1;
            const int y0 = (int)fy, x0 = (int)fx;
            const bool cx0 = (x0 >= 0) && (x0 < Wn);
            const bool cx1 = (x0 >= -1) && (x0 < Wn - 1);
            const float wr[2] = { wy0, wy1 };
            float wout[4]; int qout[2], iout[2];
            #pragma unroll
            for (int j = 0; j < 2; ++j) {
                const int yr = y0 + j;
                const bool rv = (yr >= 0) && (yr < Hn);
                wout[2 * j]     = (rv && cx0) ? wr[j] * wx0 * m : 0.f;
                wout[2 * j + 1] = (rv && cx1) ? wr[j] * wx1 * m : 0.f;
                int qv;
                if (!rv || (!cx0 && !cx1)) qv = r0 << 8;   // junk: w=0, reads pad
                else                       qv = (yr << 8) | (x0 + 1);
                const int row = qv >> 8;
                const bool inband = (row >= r0) && (row < r0 + BANDH);
                qout[j] = inband ? qv : ~qv;               // ~qv (neg) if oob
                const int rl = min(max(row - r0, 0), BANDH - 1);  // clamped
                iout[j] = (rl << 6) + (qv & 255) + 7;      // always in-bounds
            }
            mw[it] = make_float4(wout[0], wout[1], wout[2], wout[3]);
            mq[it] = make_int2(qout[0], qout[1]);
            mi[it] = make_int2(iout[0], iout[1]);
        }
    }

    // ---- write band 0; zero band pads; zero ash k-pad dwords 72..79 ----
    {
        #pragma unroll
        for (int it = 0; it < 5; ++it) {
            const int row = (tid + it * BDIM) >> 7;
            u32* d = &pband[s_pair * XSTP + row * 64 + 8 + (s_px4 << 2)];
            *(uint4*)d = make_uint4(pk2bf(bnda[it].x, bndb[it].x),
                                    pk2bf(bnda[it].y, bndb[it].y),
                                    pk2bf(bnda[it].z, bndb[it].z),
                                    pk2bf(bnda[it].w, bndb[it].w));
        }
        if (tid < 128) {   // zero lead/tail pads
            const int pr = tid >> 4, ws = tid & 15;
            pband[pr * XSTP + (ws < 8 ? ws : 640 + ws)] = 0;
        }
        ashw[(tid >> 3) * ASTW + 72 + (tid & 7)] = 0;
    }
    __syncthreads();

    const int wv = tid >> 6, ln = tid & 63, quad = ln >> 4, l16 = ln & 15;
    const u16* wrow0 = wbf + (size_t)(wv * 32 + l16) * KTOT;

    f32x4 acc[2][2];
    #pragma unroll
    for (int mt = 0; mt < 2; ++mt)
        #pragma unroll
        for (int nt = 0; nt < 2; ++nt) acc[mt][nt] = (f32x4){0.f, 0.f, 0.f, 0.f};

    for (int g = 0; g < NG; ++g) {
        // ---- sampling: LDS band (clamped, always) + per-LANE rare global fixup ----
        #pragma unroll
        for (int it = 0; it < 2; ++it) {
            const int e = tid + it * BDIM;
            if (e < ME) {
                const int t = e >> 5, px = e & 31;
                const float4 w  = mw[it];
                const int2   q  = mq[it];
                const int2   ix = mi[it];
                u32 ct0[8], ct1[8], cb0[8], cb1[8];
                #pragma unroll
                for (int c2 = 0; c2 < 8; ++c2) {
                    const u32* pc = &pband[c2 * XSTP];
                    ct0[c2] = pc[ix.x]; ct1[c2] = pc[ix.x + 1];
                    cb0[c2] = pc[ix.y]; cb1[c2] = pc[ix.y + 1];
                }
                if (q.x < 0) {   // top corner-row out of band: ~2% of lanes
                    const int qv = ~q.x, yr = qv >> 8, xx = (qv & 255) - 1;
                    const int a0 = max(xx, 0), a1 = min(xx + 1, Wn - 1);
                    const float* gp = x + (((size_t)(b * Cn + g * CG)) << 12) + yr * Wn;
                    #pragma unroll
                    for (int c2 = 0; c2 < 8; ++c2) {
                        const float* g0 = gp + ((2 * c2) << 12);
                        ct0[c2] = pk2bf(g0[a0], g0[4096 + a0]);
                        ct1[c2] = pk2bf(g0[a1], g0[4096 + a1]);
                    }
                }
                if (q.y < 0) {   // bottom corner-row out of band
                    const int qv = ~q.y, yr = qv >> 8, xx = (qv & 255) - 1;
                    const int a0 = max(xx, 0), a1 = min(xx + 1, Wn - 1);
                    const float* gp = x + (((size_t)(b * Cn + g * CG)) << 12) + yr * Wn;
                    #pragma unroll
                    for (int c2 = 0; c2 < 8; ++c2) {
                        const float* g0 = gp + ((2 * c2) << 12);
                        cb0[c2] = pk2bf(g0[a0], g0[4096 + a0]);
                        cb1[c2] = pk2bf(g0[a1], g0[4096 + a1]);
                    }
                }
                u32 avp[8];
                #pragma unroll
                for (int c2 = 0; c2 < 8; ++c2) {
                    const float va = fmaf(w.x, bflo(ct0[c2]), fmaf(w.y, bflo(ct1[c2]),
                                     fmaf(w.z, bflo(cb0[c2]), w.w * bflo(cb1[c2]))));
                    const float vb = fmaf(w.x, bfhi(ct0[c2]), fmaf(w.y, bfhi(ct1[c2]),
                                     fmaf(w.z, bfhi(cb0[c2]), w.w * bfhi(cb1[c2]))));
                    avp[c2] = pk2bf(va, vb);
                }
                u32* d = &ashw[px * ASTW + (t << 3)];
                *(uint4*)d       = make_uint4(avp[0], avp[1], avp[2], avp[3]);
                *(uint4*)(d + 4) = make_uint4(avp[4], avp[5], avp[6], avp[7]);
            }
        }
        __syncthreads();

        // ---- issue next band's global loads (drain during MFMA) ----
        if (g + 1 < NG) {
            #pragma unroll
            for (int it = 0; it < 5; ++it) {
                const int row = (tid + it * BDIM) >> 7;
                const float* base = x + (((size_t)(b * Cn + (g + 1) * CG + 2 * s_pair)) << 12)
                                    + (r0 + row) * Wn + (s_px4 << 2);
                bnda[it] = *(const float4*)base;
                bndb[it] = *(const float4*)(base + 4096);
            }
        }

        // ---- MFMA: 5 K-steps of 32; A from L2 (wbf), B via ds_read_b128 ----
        #pragma unroll
        for (int s = 0; s < 5; ++s) {
            const int kg = g * KG + s * 32 + quad * 8;
            const int kd = s * 16 + quad * 4;            // dword idx into ash row
            const bf16x8 a0 = *(const bf16x8*)(wrow0 + kg);
            const bf16x8 a1 = *(const bf16x8*)(wrow0 + 16 * KTOT + kg);
            union BF { uint4 u; bf16x8 v; } b0, b1;
            b0.u = *(const uint4*)&ashw[(0 * 16 + l16) * ASTW + kd];
            b1.u = *(const uint4*)&ashw[(1 * 16 + l16) * ASTW + kd];
            acc[0][0] = __builtin_amdgcn_mfma_f32_16x16x32_bf16(a0, b0.v, acc[0][0], 0, 0, 0);
            acc[0][1] = __builtin_amdgcn_mfma_f32_16x16x32_bf16(a0, b1.v, acc[0][1], 0, 0, 0);
            acc[1][0] = __builtin_amdgcn_mfma_f32_16x16x32_bf16(a1, b0.v, acc[1][0], 0, 0, 0);
            acc[1][1] = __builtin_amdgcn_mfma_f32_16x16x32_bf16(a1, b1.v, acc[1][1], 0, 0, 0);
        }

        // ---- write next band into pband (aligned uint4) ----
        if (g + 1 < NG) {
            #pragma unroll
            for (int it = 0; it < 5; ++it) {
                const int row = (tid + it * BDIM) >> 7;
                u32* d = &pband[s_pair * XSTP + row * 64 + 8 + (s_px4 << 2)];
                *(uint4*)d = make_uint4(pk2bf(bnda[it].x, bndb[it].x),
                                        pk2bf(bnda[it].y, bndb[it].y),
                                        pk2bf(bnda[it].z, bndb[it].z),
                                        pk2bf(bnda[it].w, bndb[it].w));
            }
        }
        __syncthreads();
    }

    // ---- epilogue: transpose via LDS (reuse pband) -> full-line stores ----
    float* tr = (float*)pband;           // 128 o x 32 px, stride 36
    #pragma unroll
    for (int mt = 0; mt < 2; ++mt)
        #pragma unroll
        for (int nt = 0; nt < 2; ++nt)
            #pragma unroll
            for (int r = 0; r < 4; ++r) {
                const int o  = wv * 32 + mt * 16 + quad * 4 + r;
                const int px = nt * 16 + l16;
                tr[o * 36 + px] = acc[mt][nt][r] + bias[o];
            }
    __syncthreads();
    float* ob = out + (size_t)b * On * Hn * Wn + h * Wn + pxbase;
    {
        const int orow = tid >> 3, ck = tid & 7;
        #pragma unroll
        for (int it = 0; it < 4; ++it) {
            const int o = it * 32 + orow;
            const float4 v = *(const float4*)&tr[o * 36 + (ck << 2)];
            *(float4*)&ob[(size_t)o * (Hn * Wn) + (ck << 2)] = v;
        }
    }
}

// ================= fallback: proven R2 fp32 kernel (no d_ws) =================
constexpr int FB_PXB = 32, FB_CCH = 4, FB_NCT = FB_CCH * KK, FB_MW = KK * FB_PXB;

#define FMA4(A, S, W)                          \
    A.x = fmaf((S).x, (W), A.x);               \
    A.y = fmaf((S).y, (W), A.y);               \
    A.z = fmaf((S).z, (W), A.z);               \
    A.w = fmaf((S).w, (W), A.w);

__global__ __launch_bounds__(BDIM, 4)
void dcn_fb_kernel(const float* __restrict__ x,
                   const float* __restrict__ offs,
                   const float* __restrict__ mask,
                   const float* __restrict__ weight,
                   const float* __restrict__ bias,
                   float* __restrict__ out)
{
    __shared__ float wmeta[4 * FB_MW];
    __shared__ int   imeta[4 * FB_MW];
    __shared__ float ssh[FB_NCT * FB_PXB];
    __shared__ float wsh[FB_NCT * On];

    const int tid    = threadIdx.x;
    const int b      = blockIdx.x & 7;
    const int rem    = blockIdx.x >> 3;
    const int h      = rem >> 1;
    const int pxbase = (rem & 1) * FB_PXB;

    for (int e = tid; e < FB_MW; e += BDIM) {
        const int t  = e >> 5;
        const int px = e & 31;
        const int pg = pxbase + px;
        const int ty = t / 3, tx = t - ty * 3;
        const float oy = offs[((b * 18 + 2 * t    ) * Hn + h) * Wn + pg];
        const float ox = offs[((b * 18 + 2 * t + 1) * Hn + h) * Wn + pg];
        const float m  = mask[((b * KK + t) * Hn + h) * Wn + pg];
        const float py = (float)(h - PAD + ty) + oy;
        const float qx = (float)(pg - PAD + tx) + ox;
        const float y0 = floorf(py), x0 = floorf(qx);
        const float wy1 = py - y0, wx1 = qx - x0;
        const float wy0 = 1.f - wy1, wx0 = 1.f - wx1;
        const float cw[4] = { wy0 * wx0, wy0 * wx1, wy1 * wx0, wy1 * wx1 };
        #pragma unroll
        for (int k = 0; k < 4; ++k) {
            const float yk = y0 + (float)(k >> 1);
            const float xk = x0 + (float)(k & 1);
            const bool valid = (yk >= 0.f) && (yk <= (float)(Hn - 1)) &&
                               (xk >= 0.f) && (xk <= (float)(Wn - 1));
            const int yc = (int)fminf(fmaxf(yk, 0.f), (float)(Hn - 1));
            const int xc = (int)fminf(fmaxf(xk, 0.f), (float)(Wn - 1));
            wmeta[k * FB_MW + e] = valid ? cw[k] * m : 0.f;
            imeta[k * FB_MW + e] = yc * Wn + xc;
        }
    }
    __syncthreads();

    const int px0 = (tid & 7) << 2;
    const int oo  = (tid >> 3) << 2;

    float4 acc[4];
    #pragma unroll
    for (int j = 0; j < 4; ++j) acc[j] = make_float4(0.f, 0.f, 0.f, 0.f);

    for (int cb = 0; cb < Cn / FB_CCH; ++cb) {
        #pragma unroll
        for (int it = 0; it < (FB_NCT * On) / BDIM; ++it) {
            const int e = tid + it * BDIM;
            const int r = e >> 7;
            const int o = e & 127;
            wsh[r * On + o] = weight[o * (Cn * KK) + cb * FB_NCT + r];
        }
        for (int e = tid; e < FB_NCT * FB_PXB; e += BDIM) {
            const int px = e & 31;
            const int ct = e >> 5;
            const int c  = ct / 9;
            const int mb = (ct - c * 9) * FB_PXB + px;
            const float* xp = x + (((b * Cn) + cb * FB_CCH + c) << 12);
            float v =  wmeta[mb]              * xp[imeta[mb]];
            v = fmaf(wmeta[FB_MW     + mb], xp[imeta[FB_MW     + mb]], v);
            v = fmaf(wmeta[2 * FB_MW + mb], xp[imeta[2 * FB_MW + mb]], v);
            v = fmaf(wmeta[3 * FB_MW + mb], xp[imeta[3 * FB_MW + mb]], v);
            ssh[ct * FB_PXB + px] = v;
        }
        __syncthreads();

        #pragma unroll 6
        for (int ct = 0; ct < FB_NCT; ++ct) {
            const float4 sv = *(const float4*)&ssh[ct * FB_PXB + px0];
            const float4 wa = *(const float4*)&wsh[ct * On + oo];
            FMA4(acc[0], sv, wa.x);
            FMA4(acc[1], sv, wa.y);
            FMA4(acc[2], sv, wa.z);
            FMA4(acc[3], sv, wa.w);
        }
        __syncthreads();
    }

    #pragma unroll
    for (int j = 0; j < 4; ++j) {
        const float bv = bias[oo + j];
        float4 r = acc[j];
        r.x += bv; r.y += bv; r.z += bv; r.w += bv;
        *(float4*)&out[((b * On + oo + j) * Hn + h) * Wn + pxbase + px0] = r;
    }
}

extern "C" void kernel_launch(void* const* d_in, const int* in_sizes, int n_in,
                              void* d_out, int out_size, void* d_ws, size_t ws_size,
                              hipStream_t stream) {
    const float* x      = (const float*)d_in[0];
    const float* offs   = (const float*)d_in[1];
    const float* mask   = (const float*)d_in[2];
    const float* weight = (const float*)d_in[3];
    const float* bias   = (const float*)d_in[4];
    float* out = (float*)d_out;

    const size_t need = (size_t)On * KTOT * sizeof(u16);   // 327,680 B
    if (d_ws != nullptr && ws_size >= need) {
        u16* wbf = (u16*)d_ws;
        wprep_kernel<<<dim3(On * KTOT / BDIM), dim3(BDIM), 0, stream>>>(weight, wbf);
        dcn_mfma_kernel<<<dim3(Bn * Hn * 2), dim3(BDIM), 0, stream>>>(
            x, offs, mask, wbf, bias, out);
    } else {
        dcn_fb_kernel<<<dim3(Bn * Hn * 2), dim3(BDIM), 0, stream>>>(
            x, offs, mask, weight, bias, out);
    }
}

// Round 10
// 154.521 us; speedup vs baseline: 1.3185x; 1.3185x over previous
//
#include <hip/hip_runtime.h>
#include <math.h>

// DCN v2: B=8, C=128, O=128, H=W=64, k=3, dil=1, dg=1, stride=1, pad=1.
// R10 == R9 with the spill fixed: __launch_bounds__(256,2) (R9's (256,4)
// forced a 64-VGPR allocation -> ~80 MB/launch scratch traffic, HBM-bound).
// Design: LDS band gathers with clamped indices + per-LANE rare global fixup;
// 16B-aligned ash (b128 MFMA B-reads); mfma_f32_16x16x32_bf16 GEMM.
constexpr int Bn = 8, Cn = 128, On = 128, Hn = 64, Wn = 64;
constexpr int KK = 9, PAD = 1, BDIM = 256;
constexpr int PXB = 32;              // pixels per block (half row)
constexpr int CG = 16;               // channels per granule
constexpr int NG = Cn / CG;          // 8
constexpr int KG = 160;              // 144 real k-slices + 16 zero pad
constexpr int KTOT = NG * KG;        // 1280
constexpr int BANDH = 10;            // band rows
constexpr int XSTP = 660;            // pband pair stride (u32), mod4=0 for b128
constexpr int ASTW = 88;             // ash k-stride in u32 (=176 bf16), 16B-aligned
constexpr int ME = KK * PXB;         // 288 (tap,px) tasks per block

typedef __attribute__((ext_vector_type(8))) short bf16x8;
typedef __attribute__((ext_vector_type(4))) float f32x4;
typedef unsigned short u16;
typedef unsigned int u32;

__device__ inline u16 f2bf(float f) {   // RNE f32->bf16
    union { float f; u32 u; } v; v.f = f;
    return (u16)((v.u + 0x7FFFu + ((v.u >> 16) & 1u)) >> 16);
}
__device__ inline u32 pk2bf(float a, float b) {   // low16 = bf16(a)
    return (u32)f2bf(a) | ((u32)f2bf(b) << 16);
}
__device__ inline float bflo(u32 w) { return __uint_as_float(w << 16); }
__device__ inline float bfhi(u32 w) { return __uint_as_float(w & 0xFFFF0000u); }

// weight [O][C*9] fp32 -> wbf [O][KTOT] bf16, k' = g*KG + t*16 + cl
__global__ void wprep_kernel(const float* __restrict__ w, u16* __restrict__ wbf) {
    const int e = blockIdx.x * BDIM + threadIdx.x;    // < 163840
    const int o  = e / KTOT;
    const int kp = e - o * KTOT;
    const int g  = kp / KG;
    const int r  = kp - g * KG;
    const int t  = r >> 4;
    const int cl = r & 15;
    float v = 0.f;
    if (t < KK) v = w[o * (Cn * KK) + (g * CG + cl) * KK + t];
    wbf[e] = f2bf(v);
}

__global__ __launch_bounds__(BDIM, 2)   // <= R10 fix: allow ~128 VGPRs, no spill
void dcn_mfma_kernel(const float* __restrict__ x,
                     const float* __restrict__ offs,
                     const float* __restrict__ mask,
                     const u16*   __restrict__ wbf,
                     const float* __restrict__ bias,
                     float* __restrict__ out)
{
    __shared__ __align__(16) u32 pband[8 * XSTP];   // 21,120 B
    __shared__ __align__(16) u32 ashw[PXB * ASTW];  // 11,264 B (tot 32.4 KB)

    const int tid    = threadIdx.x;
    const int b      = blockIdx.x & 7;          // batch<->XCD affinity
    const int rem    = blockIdx.x >> 3;
    const int h      = rem >> 1;
    const int pxbase = (rem & 1) * PXB;
    const int r0     = min(max(h - 4, 0), Hn - BANDH);

    // band task map: tau = tid + it*256 -> px4=tau&15, pair const, row=tau>>7
    const int s_px4  = tid & 15;
    const int s_pair = (tid >> 4) & 7;
    float4 bnda[5], bndb[5];
    {   // issue granule-0 band loads early
        #pragma unroll
        for (int it = 0; it < 5; ++it) {
            const int row = (tid + it * BDIM) >> 7;
            const float* base = x + (((size_t)(b * Cn + 2 * s_pair)) << 12)
                                + (r0 + row) * Wn + (s_px4 << 2);
            bnda[it] = *(const float4*)base;
            bndb[it] = *(const float4*)(base + 4096);
        }
    }

    // ---- meta in registers: weights mw, oob-coded coords mq, CLAMPED LDS idx mi ----
    float4 mw[2]; int2 mq[2]; int2 mi[2];
    #pragma unroll
    for (int it = 0; it < 2; ++it) {
        mw[it] = make_float4(0.f, 0.f, 0.f, 0.f);
        mq[it] = make_int2(0, 0);
        mi[it] = make_int2(7, 7);
        const int e = tid + it * BDIM;
        if (e < ME) {
            const int t = e >> 5, px = e & 31, pg = pxbase + px;
            const int ty = t / 3, tx = t - ty * 3;
            const float oy = offs[((b * 18 + 2 * t    ) * Hn + h) * Wn + pg];
            const float ox = offs[((b * 18 + 2 * t + 1) * Hn + h) * Wn + pg];
            const float m  = mask[((b * KK + t) * Hn + h) * Wn + pg];
            const float py = (float)(h - PAD + ty) + oy;
            const float qx = (float)(pg - PAD + tx) + ox;
            const float fy = floorf(py), fx = floorf(qx);
            const float wy1 = py - fy, wx1 = qx - fx;
            const float wy0 = 1.f - wy1, wx0 = 1.f - wx1;
            const int y0 = (int)fy, x0 = (int)fx;
            const bool cx0 = (x0 >= 0) && (x0 < Wn);
            const bool cx1 = (x0 >= -1) && (x0 < Wn - 1);
            const float wr[2] = { wy0, wy1 };
            float wout[4]; int qout[2], iout[2];
            #pragma unroll
            for (int j = 0; j < 2; ++j) {
                const int yr = y0 + j;
                const bool rv = (yr >= 0) && (yr < Hn);
                wout[2 * j]     = (rv && cx0) ? wr[j] * wx0 * m : 0.f;
                wout[2 * j + 1] = (rv && cx1) ? wr[j] * wx1 * m : 0.f;
                int qv;
                if (!rv || (!cx0 && !cx1)) qv = r0 << 8;   // junk: w=0, reads pad
                else                       qv = (yr << 8) | (x0 + 1);
                const int row = qv >> 8;
                const bool inband = (row >= r0) && (row < r0 + BANDH);
                qout[j] = inband ? qv : ~qv;               // ~qv (neg) if oob
                const int rl = min(max(row - r0, 0), BANDH - 1);  // clamped
                iout[j] = (rl << 6) + (qv & 255) + 7;      // always in-bounds
            }
            mw[it] = make_float4(wout[0], wout[1], wout[2], wout[3]);
            mq[it] = make_int2(qout[0], qout[1]);
            mi[it] = make_int2(iout[0], iout[1]);
        }
    }

    // ---- write band 0; zero band pads; zero ash k-pad dwords 72..79 ----
    {
        #pragma unroll
        for (int it = 0; it < 5; ++it) {
            const int row = (tid + it * BDIM) >> 7;
            u32* d = &pband[s_pair * XSTP + row * 64 + 8 + (s_px4 << 2)];
            *(uint4*)d = make_uint4(pk2bf(bnda[it].x, bndb[it].x),
                                    pk2bf(bnda[it].y, bndb[it].y),
                                    pk2bf(bnda[it].z, bndb[it].z),
                                    pk2bf(bnda[it].w, bndb[it].w));
        }
        if (tid < 128) {   // zero lead/tail pads
            const int pr = tid >> 4, ws = tid & 15;
            pband[pr * XSTP + (ws < 8 ? ws : 640 + ws)] = 0;
        }
        ashw[(tid >> 3) * ASTW + 72 + (tid & 7)] = 0;
    }
    __syncthreads();

    const int wv = tid >> 6, ln = tid & 63, quad = ln >> 4, l16 = ln & 15;
    const u16* wrow0 = wbf + (size_t)(wv * 32 + l16) * KTOT;

    f32x4 acc[2][2];
    #pragma unroll
    for (int mt = 0; mt < 2; ++mt)
        #pragma unroll
        for (int nt = 0; nt < 2; ++nt) acc[mt][nt] = (f32x4){0.f, 0.f, 0.f, 0.f};

    for (int g = 0; g < NG; ++g) {
        // ---- sampling: LDS band (clamped, always) + per-LANE rare global fixup ----
        #pragma unroll
        for (int it = 0; it < 2; ++it) {
            const int e = tid + it * BDIM;
            if (e < ME) {
                const int t = e >> 5, px = e & 31;
                const float4 w  = mw[it];
                const int2   q  = mq[it];
                const int2   ix = mi[it];
                u32 ct0[8], ct1[8], cb0[8], cb1[8];
                #pragma unroll
                for (int c2 = 0; c2 < 8; ++c2) {
                    const u32* pc = &pband[c2 * XSTP];
                    ct0[c2] = pc[ix.x]; ct1[c2] = pc[ix.x + 1];
                    cb0[c2] = pc[ix.y]; cb1[c2] = pc[ix.y + 1];
                }
                if (q.x < 0) {   // top corner-row out of band: ~2% of lanes
                    const int qv = ~q.x, yr = qv >> 8, xx = (qv & 255) - 1;
                    const int a0 = max(xx, 0), a1 = min(xx + 1, Wn - 1);
                    const float* gp = x + (((size_t)(b * Cn + g * CG)) << 12) + yr * Wn;
                    #pragma unroll
                    for (int c2 = 0; c2 < 8; ++c2) {
                        const float* g0 = gp + ((2 * c2) << 12);
                        ct0[c2] = pk2bf(g0[a0], g0[4096 + a0]);
                        ct1[c2] = pk2bf(g0[a1], g0[4096 + a1]);
                    }
                }
                if (q.y < 0) {   // bottom corner-row out of band
                    const int qv = ~q.y, yr = qv >> 8, xx = (qv & 255) - 1;
                    const int a0 = max(xx, 0), a1 = min(xx + 1, Wn - 1);
                    const float* gp = x + (((size_t)(b * Cn + g * CG)) << 12) + yr * Wn;
                    #pragma unroll
                    for (int c2 = 0; c2 < 8; ++c2) {
                        const float* g0 = gp + ((2 * c2) << 12);
                        cb0[c2] = pk2bf(g0[a0], g0[4096 + a0]);
                        cb1[c2] = pk2bf(g0[a1], g0[4096 + a1]);
                    }
                }
                u32 avp[8];
                #pragma unroll
                for (int c2 = 0; c2 < 8; ++c2) {
                    const float va = fmaf(w.x, bflo(ct0[c2]), fmaf(w.y, bflo(ct1[c2]),
                                     fmaf(w.z, bflo(cb0[c2]), w.w * bflo(cb1[c2]))));
                    const float vb = fmaf(w.x, bfhi(ct0[c2]), fmaf(w.y, bfhi(ct1[c2]),
                                     fmaf(w.z, bfhi(cb0[c2]), w.w * bfhi(cb1[c2]))));
                    avp[c2] = pk2bf(va, vb);
                }
                u32* d = &ashw[px * ASTW + (t << 3)];
                *(uint4*)d       = make_uint4(avp[0], avp[1], avp[2], avp[3]);
                *(uint4*)(d + 4) = make_uint4(avp[4], avp[5], avp[6], avp[7]);
            }
        }
        __syncthreads();

        // ---- issue next band's global loads (drain during MFMA) ----
        if (g + 1 < NG) {
            #pragma unroll
            for (int it = 0; it < 5; ++it) {
                const int row = (tid + it * BDIM) >> 7;
                const float* base = x + (((size_t)(b * Cn + (g + 1) * CG + 2 * s_pair)) << 12)
                                    + (r0 + row) * Wn + (s_px4 << 2);
                bnda[it] = *(const float4*)base;
                bndb[it] = *(const float4*)(base + 4096);
            }
        }

        // ---- MFMA: 5 K-steps of 32; A from L2 (wbf), B via ds_read_b128 ----
        #pragma unroll
        for (int s = 0; s < 5; ++s) {
            const int kg = g * KG + s * 32 + quad * 8;
            const int kd = s * 16 + quad * 4;            // dword idx into ash row
            const bf16x8 a0 = *(const bf16x8*)(wrow0 + kg);
            const bf16x8 a1 = *(const bf16x8*)(wrow0 + 16 * KTOT + kg);
            union BF { uint4 u; bf16x8 v; } b0, b1;
            b0.u = *(const uint4*)&ashw[(0 * 16 + l16) * ASTW + kd];
            b1.u = *(const uint4*)&ashw[(1 * 16 + l16) * ASTW + kd];
            acc[0][0] = __builtin_amdgcn_mfma_f32_16x16x32_bf16(a0, b0.v, acc[0][0], 0, 0, 0);
            acc[0][1] = __builtin_amdgcn_mfma_f32_16x16x32_bf16(a0, b1.v, acc[0][1], 0, 0, 0);
            acc[1][0] = __builtin_amdgcn_mfma_f32_16x16x32_bf16(a1, b0.v, acc[1][0], 0, 0, 0);
            acc[1][1] = __builtin_amdgcn_mfma_f32_16x16x32_bf16(a1, b1.v, acc[1][1], 0, 0, 0);
        }

        // ---- write next band into pband (aligned uint4) ----
        if (g + 1 < NG) {
            #pragma unroll
            for (int it = 0; it < 5; ++it) {
                const int row = (tid + it * BDIM) >> 7;
                u32* d = &pband[s_pair * XSTP + row * 64 + 8 + (s_px4 << 2)];
                *(uint4*)d = make_uint4(pk2bf(bnda[it].x, bndb[it].x),
                                        pk2bf(bnda[it].y, bndb[it].y),
                                        pk2bf(bnda[it].z, bndb[it].z),
                                        pk2bf(bnda[it].w, bndb[it].w));
            }
        }
        __syncthreads();
    }

    // ---- epilogue: transpose via LDS (reuse pband) -> full-line stores ----
    float* tr = (float*)pband;           // 128 o x 32 px, stride 36
    #pragma unroll
    for (int mt = 0; mt < 2; ++mt)
        #pragma unroll
        for (int nt = 0; nt < 2; ++nt)
            #pragma unroll
            for (int r = 0; r < 4; ++r) {
                const int o  = wv * 32 + mt * 16 + quad * 4 + r;
                const int px = nt * 16 + l16;
                tr[o * 36 + px] = acc[mt][nt][r] + bias[o];
            }
    __syncthreads();
    float* ob = out + (size_t)b * On * Hn * Wn + h * Wn + pxbase;
    {
        const int orow = tid >> 3, ck = tid & 7;
        #pragma unroll
        for (int it = 0; it < 4; ++it) {
            const int o = it * 32 + orow;
            const float4 v = *(const float4*)&tr[o * 36 + (ck << 2)];
            *(float4*)&ob[(size_t)o * (Hn * Wn) + (ck << 2)] = v;
        }
    }
}

// ================= fallback: proven R2 fp32 kernel (no d_ws) =================
constexpr int FB_PXB = 32, FB_CCH = 4, FB_NCT = FB_CCH * KK, FB_MW = KK * FB_PXB;

#define FMA4(A, S, W)                          \
    A.x = fmaf((S).x, (W), A.x);               \
    A.y = fmaf((S).y, (W), A.y);               \
    A.z = fmaf((S).z, (W), A.z);               \
    A.w = fmaf((S).w, (W), A.w);

__global__ __launch_bounds__(BDIM, 4)
void dcn_fb_kernel(const float* __restrict__ x,
                   const float* __restrict__ offs,
                   const float* __restrict__ mask,
                   const float* __restrict__ weight,
                   const float* __restrict__ bias,
                   float* __restrict__ out)
{
    __shared__ float wmeta[4 * FB_MW];
    __shared__ int   imeta[4 * FB_MW];
    __shared__ float ssh[FB_NCT * FB_PXB];
    __shared__ float wsh[FB_NCT * On];

    const int tid    = threadIdx.x;
    const int b      = blockIdx.x & 7;
    const int rem    = blockIdx.x >> 3;
    const int h      = rem >> 1;
    const int pxbase = (rem & 1) * FB_PXB;

    for (int e = tid; e < FB_MW; e += BDIM) {
        const int t  = e >> 5;
        const int px = e & 31;
        const int pg = pxbase + px;
        const int ty = t / 3, tx = t - ty * 3;
        const float oy = offs[((b * 18 + 2 * t    ) * Hn + h) * Wn + pg];
        const float ox = offs[((b * 18 + 2 * t + 1) * Hn + h) * Wn + pg];
        const float m  = mask[((b * KK + t) * Hn + h) * Wn + pg];
        const float py = (float)(h - PAD + ty) + oy;
        const float qx = (float)(pg - PAD + tx) + ox;
        const float y0 = floorf(py), x0 = floorf(qx);
        const float wy1 = py - y0, wx1 = qx - x0;
        const float wy0 = 1.f - wy1, wx0 = 1.f - wx1;
        const float cw[4] = { wy0 * wx0, wy0 * wx1, wy1 * wx0, wy1 * wx1 };
        #pragma unroll
        for (int k = 0; k < 4; ++k) {
            const float yk = y0 + (float)(k >> 1);
            const float xk = x0 + (float)(k & 1);
            const bool valid = (yk >= 0.f) && (yk <= (float)(Hn - 1)) &&
                               (xk >= 0.f) && (xk <= (float)(Wn - 1));
            const int yc = (int)fminf(fmaxf(yk, 0.f), (float)(Hn - 1));
            const int xc = (int)fminf(fmaxf(xk, 0.f), (float)(Wn - 1));
            wmeta[k * FB_MW + e] = valid ? cw[k] * m : 0.f;
            imeta[k * FB_MW + e] = yc * Wn + xc;
        }
    }
    __syncthreads();

    const int px0 = (tid & 7) << 2;
    const int oo  = (tid >> 3) << 2;

    float4 acc[4];
    #pragma unroll
    for (int j = 0; j < 4; ++j) acc[j] = make_float4(0.f, 0.f, 0.f, 0.f);

    for (int cb = 0; cb < Cn / FB_CCH; ++cb) {
        #pragma unroll
        for (int it = 0; it < (FB_NCT * On) / BDIM; ++it) {
            const int e = tid + it * BDIM;
            const int r = e >> 7;
            const int o = e & 127;
            wsh[r * On + o] = weight[o * (Cn * KK) + cb * FB_NCT + r];
        }
        for (int e = tid; e < FB_NCT * FB_PXB; e += BDIM) {
            const int px = e & 31;
            const int ct = e >> 5;
            const int c  = ct / 9;
            const int mb = (ct - c * 9) * FB_PXB + px;
            const float* xp = x + (((b * Cn) + cb * FB_CCH + c) << 12);
            float v =  wmeta[mb]              * xp[imeta[mb]];
            v = fmaf(wmeta[FB_MW     + mb], xp[imeta[FB_MW     + mb]], v);
            v = fmaf(wmeta[2 * FB_MW + mb], xp[imeta[2 * FB_MW + mb]], v);
            v = fmaf(wmeta[3 * FB_MW + mb], xp[imeta[3 * FB_MW + mb]], v);
            ssh[ct * FB_PXB + px] = v;
        }
        __syncthreads();

        #pragma unroll 6
        for (int ct = 0; ct < FB_NCT; ++ct) {
            const float4 sv = *(const float4*)&ssh[ct * FB_PXB + px0];
            const float4 wa = *(const float4*)&wsh[ct * On + oo];
            FMA4(acc[0], sv, wa.x);
            FMA4(acc[1], sv, wa.y);
            FMA4(acc[2], sv, wa.z);
            FMA4(acc[3], sv, wa.w);
        }
        __syncthreads();
    }

    #pragma unroll
    for (int j = 0; j < 4; ++j) {
        const float bv = bias[oo + j];
        float4 r = acc[j];
        r.x += bv; r.y += bv; r.z += bv; r.w += bv;
        *(float4*)&out[((b * On + oo + j) * Hn + h) * Wn + pxbase + px0] = r;
    }
}

extern "C" void kernel_launch(void* const* d_in, const int* in_sizes, int n_in,
                              void* d_out, int out_size, void* d_ws, size_t ws_size,
                              hipStream_t stream) {
    const float* x      = (const float*)d_in[0];
    const float* offs   = (const float*)d_in[1];
    const float* mask   = (const float*)d_in[2];
    const float* weight = (const float*)d_in[3];
    const float* bias   = (const float*)d_in[4];
    float* out = (float*)d_out;

    const size_t need = (size_t)On * KTOT * sizeof(u16);   // 327,680 B
    if (d_ws != nullptr && ws_size >= need) {
        u16* wbf = (u16*)d_ws;
        wprep_kernel<<<dim3(On * KTOT / BDIM), dim3(BDIM), 0, stream>>>(weight, wbf);
        dcn_mfma_kernel<<<dim3(Bn * Hn * 2), dim3(BDIM), 0, stream>>>(
            x, offs, mask, wbf, bias, out);
    } else {
        dcn_fb_kernel<<<dim3(Bn * Hn * 2), dim3(BDIM), 0, stream>>>(
            x, offs, mask, weight, bias, out);
    }
}